// Round 3
// baseline (639.015 us; speedup 1.0000x reference)
//
#include <hip/hip_runtime.h>

static constexpr int T_STEPS = 512;
static constexpr int NBATCH  = 256;
static constexpr int DD      = 128;                         // C = D = K = 128
static constexpr long TND    = (long)T_STEPS * NBATCH * DD; // elems per output tensor

typedef short bf16x8 __attribute__((ext_vector_type(8)));   // 8 bf16 in 4 VGPRs
typedef float f32x4  __attribute__((ext_vector_type(4)));
typedef unsigned u32x4 __attribute__((ext_vector_type(4)));

__device__ inline unsigned short f2bf(float f) {            // RNE fp32 -> bf16
  unsigned u = __builtin_bit_cast(unsigned, f);
  unsigned r = u + 0x7FFFu + ((u >> 16) & 1u);
  return (unsigned short)(r >> 16);
}

__device__ inline bf16x8 pack8(const float* s) {
  bf16x8 v;
#pragma unroll
  for (int i = 0; i < 8; ++i) v[i] = (short)f2bf(s[i]);
  return v;
}

// v_cvt_pk_bf16_f32: D.lo = bf16(lo), D.hi = bf16(hi), RNE (gfx950).
__device__ __forceinline__ unsigned cvtpk_bf16(float lo, float hi) {
  unsigned r;
  asm("v_cvt_pk_bf16_f32 %0, %1, %2" : "=v"(r) : "v"(lo), "v"(hi));
  return r;
}

// ---------------------------------------------------------------------------
// Phase 3: O[M x 128] = A[M x 128] @ W^T + bias via bf16 MFMA, fp32 accum.
// One wave owns all of W as 32 register-resident B-fragments (128 VGPRs),
// then grid-strides over 16-row tiles: 8 A-loads + 32 MFMA + 32 stores/tile.
// ---------------------------------------------------------------------------
__global__ __launch_bounds__(256) void gemm128_mfma(
    const float* __restrict__ A, const float* __restrict__ W,
    const float* __restrict__ bias, float* __restrict__ O, int ntiles) {
  const int lane = threadIdx.x & 63;
  const int wib  = threadIdx.x >> 6;     // wave in block (0..3)
  const int m    = lane & 15;            // row-in-tile / W-row-in-dtile
  const int q    = lane >> 4;            // quad: k-octet selector, C row group

  bf16x8 Wf[8][4];
#pragma unroll
  for (int j = 0; j < 8; ++j)
#pragma unroll
    for (int kq = 0; kq < 4; ++kq) {
      const float* p = W + (j * 16 + m) * DD + kq * 32 + q * 8;
      float t[8];
      *(float4*)&t[0] = *(const float4*)p;
      *(float4*)&t[4] = *(const float4*)(p + 4);
      Wf[j][kq] = pack8(t);
    }
  float bv[8];
#pragma unroll
  for (int j = 0; j < 8; ++j) bv[j] = bias[j * 16 + m];

  const int wglobal = blockIdx.x * 4 + wib;
  const int nwaves  = gridDim.x * 4;
  for (int tile = wglobal; tile < ntiles; tile += nwaves) {
    const long r0 = (long)tile * 16;
    f32x4 acc[8];
#pragma unroll
    for (int j = 0; j < 8; ++j) acc[j] = (f32x4){0.f, 0.f, 0.f, 0.f};

#pragma unroll
    for (int kq = 0; kq < 4; ++kq) {
      const float* p = A + (r0 + m) * DD + kq * 32 + q * 8;
      float t[8];
      *(float4*)&t[0] = *(const float4*)p;
      *(float4*)&t[4] = *(const float4*)(p + 4);
      bf16x8 af = pack8(t);
#pragma unroll
      for (int j = 0; j < 8; ++j)
        acc[j] = __builtin_amdgcn_mfma_f32_16x16x32_bf16(af, Wf[j][kq], acc[j], 0, 0, 0);
    }
#pragma unroll
    for (int j = 0; j < 8; ++j)
#pragma unroll
      for (int r = 0; r < 4; ++r)
        O[(r0 + q * 4 + r) * DD + j * 16 + m] = acc[j][r] + bv[j];
  }
}

// ---------------------------------------------------------------------------
// Phase 1+2 FUSED: scan on the matrix pipe, one wave per 16 batch rows,
// computing xp_t = Wx @ x_t^T + bx on the fly (32 extra MFMAs, off the
// h-critical-path) instead of reading a precomputed xproj buffer.
//   - kills the in-place H load/store alias pattern that exposed ~1100 cy
//     of memory latency per step in the previous version (loads now stream
//     from read-only x; stores to H are fire-and-forget, disjoint buffers);
//   - kills the GEMM1 dispatch entirely.
// h-recurrence (verified in R2): D[d][n] = sum_k Wh[d][k] h[n][k]; per-q
// k-permutation kappa applied to BOTH Wh gather and h feedback makes the
// step's D quads (packed via cvt_pk) directly the next step's B-frags —
// no shuffle/LDS/barrier anywhere.
// x-GEMM uses the standard slot layout (k = 32kq + 8q + s) on both sides;
// its D-layout (row d = 16j+4q+r, col n = m) matches the h-GEMM's, so
// acc composes: acc = bxv -> + x-MFMAs -> + h-MFMAs -> relu -> h.
// ---------------------------------------------------------------------------
__global__ __launch_bounds__(64, 1) void rnn_scan_fused(
    const float* __restrict__ x,  const float* __restrict__ Wx,
    const float* __restrict__ bx, const float* __restrict__ Wh,
    float* __restrict__ H /* [T][N][128] output: all_h */) {
  const int lane = threadIdx.x & 63;
  const int m = lane & 15;   // batch row within the wave's 16-row group
  const int q = lane >> 4;   // quad

  // Wx A-frags, standard slot k = 32kq + 8q + s
  bf16x8 Wxf[8][4];
#pragma unroll
  for (int j = 0; j < 8; ++j)
#pragma unroll
    for (int kq = 0; kq < 4; ++kq) {
      const float* p = Wx + (j * 16 + m) * DD + kq * 32 + q * 8;
      float t[8];
      *(float4*)&t[0] = *(const float4*)p;
      *(float4*)&t[4] = *(const float4*)(p + 4);
      Wxf[j][kq] = pack8(t);
    }

  // Wh A-frags with the q-dependent kappa gather:
  // s<4 -> Wh[16j+m][32kq + 4q + s]; s>=4 -> Wh[16j+m][32kq + 16 + 4q + (s-4)]
  bf16x8 Whf[8][4];
#pragma unroll
  for (int j = 0; j < 8; ++j)
#pragma unroll
    for (int kq = 0; kq < 4; ++kq) {
      const float* p = Wh + (j * 16 + m) * DD + kq * 32 + 4 * q;
      float t[8];
      *(float4*)&t[0] = *(const float4*)p;
      *(float4*)&t[4] = *(const float4*)(p + 16);
      Whf[j][kq] = pack8(t);
    }

  // bias fragment in the D-layout: bxv[j][r] = bx[16j + 4q + r]
  f32x4 bxv[8];
#pragma unroll
  for (int j = 0; j < 8; ++j) bxv[j] = *(const f32x4*)(bx + j * 16 + 4 * q);

  const long stepN = (long)NBATCH * DD;
  const float* xb = x + (long)(blockIdx.x * 16 + m) * DD + 8 * q;  // B-side x gather
  float*       hb = H + (long)(blockIdx.x * 16 + m) * DD + 4 * q;  // D-side h store

  // h feedback in kappa layout: w[j][hw] = bf16x2(h[m][16j+4q+2hw(+1)]); h_-1=0
  unsigned w[8][2];
#pragma unroll
  for (int j = 0; j < 8; ++j) { w[j][0] = 0u; w[j][1] = 0u; }

  auto pref = [&](f32x4 (&r)[8], int t) {   // raw x row, 8 x float4
    const float* p = xb + (long)t * stepN;
#pragma unroll
    for (int kq = 0; kq < 4; ++kq) {
      r[2 * kq]     = *(const f32x4*)(p + kq * 32);
      r[2 * kq + 1] = *(const f32x4*)(p + kq * 32 + 4);
    }
  };

  auto step = [&](const f32x4 (&r)[8], int t) {
    // pack this step's x into B-frags (standard slot layout)
    bf16x8 xf[4];
#pragma unroll
    for (int kq = 0; kq < 4; ++kq) {
      u32x4 u;
      u[0] = cvtpk_bf16(r[2 * kq][0],     r[2 * kq][1]);
      u[1] = cvtpk_bf16(r[2 * kq][2],     r[2 * kq][3]);
      u[2] = cvtpk_bf16(r[2 * kq + 1][0], r[2 * kq + 1][1]);
      u[3] = cvtpk_bf16(r[2 * kq + 1][2], r[2 * kq + 1][3]);
      xf[kq] = __builtin_bit_cast(bf16x8, u);
    }
    // acc = bx + Wx x_t^T   (independent of h -> fills the pipe)
    f32x4 acc[8];
#pragma unroll
    for (int j = 0; j < 8; ++j)
      acc[j] = __builtin_amdgcn_mfma_f32_16x16x32_bf16(Wxf[j][0], xf[0], bxv[j], 0, 0, 0);
#pragma unroll
    for (int kq = 1; kq < 4; ++kq)
#pragma unroll
      for (int j = 0; j < 8; ++j)
        acc[j] = __builtin_amdgcn_mfma_f32_16x16x32_bf16(Wxf[j][kq], xf[kq], acc[j], 0, 0, 0);
    // acc += Wh h^T  (B-frags are last step's packed D quads — zero movement)
#pragma unroll
    for (int kq = 0; kq < 4; ++kq) {
      u32x4 bw;
      bw[0] = w[2 * kq][0];     bw[1] = w[2 * kq][1];
      bw[2] = w[2 * kq + 1][0]; bw[3] = w[2 * kq + 1][1];
      bf16x8 bf = __builtin_bit_cast(bf16x8, bw);
#pragma unroll
      for (int j = 0; j < 8; ++j)
        acc[j] = __builtin_amdgcn_mfma_f32_16x16x32_bf16(Whf[j][kq], bf, acc[j], 0, 0, 0);
    }
    // relu, repack feedback, store fp32 h
    float* hp = hb + (long)t * stepN;
#pragma unroll
    for (int j = 0; j < 8; ++j) {
      f32x4 hv;
#pragma unroll
      for (int rr = 0; rr < 4; ++rr) hv[rr] = fmaxf(acc[j][rr], 0.f);
      w[j][0] = cvtpk_bf16(hv[0], hv[1]);
      w[j][1] = cvtpk_bf16(hv[2], hv[3]);
      *(f32x4*)(hp + j * 16) = hv;
    }
  };

  f32x4 xA[8], xB[8], xC[8], xD[8];   // 4-deep named prefetch ring (~4 steps ahead)
  pref(xA, 0); pref(xB, 1); pref(xC, 2); pref(xD, 3);

#pragma unroll 1
  for (int t = 0; t < T_STEPS; t += 4) {
    step(xA, t);     pref(xA, t + 4 < T_STEPS ? t + 4 : T_STEPS - 1);
    step(xB, t + 1); pref(xB, t + 5 < T_STEPS ? t + 5 : T_STEPS - 1);
    step(xC, t + 2); pref(xC, t + 6 < T_STEPS ? t + 6 : T_STEPS - 1);
    step(xD, t + 3); pref(xD, t + 7 < T_STEPS ? t + 7 : T_STEPS - 1);
  }
}

// ---------------------------------------------------------------------------
extern "C" void kernel_launch(void* const* d_in, const int* in_sizes, int n_in,
                              void* d_out, int out_size, void* d_ws, size_t ws_size,
                              hipStream_t stream) {
  const float* x  = (const float*)d_in[0];   // (T,N,C)
  const float* Wx = (const float*)d_in[1];   // (D,C)
  const float* bx = (const float*)d_in[2];   // (D)
  const float* Wh = (const float*)d_in[3];   // (D,D)
  const float* Wy = (const float*)d_in[4];   // (K,D)
  const float* by = (const float*)d_in[5];   // (K)

  float* Y = (float*)d_out;        // all_y: [T][N][K]
  float* H = (float*)d_out + TND;  // all_h: [T][N][D]

  const int ntiles = T_STEPS * NBATCH / 16;  // 8192 row-tiles

  rnn_scan_fused<<<NBATCH / 16, 64, 0, stream>>>(x, Wx, bx, Wh, H);  // x -> all_h
  gemm128_mfma<<<512, 256, 0, stream>>>(H, Wy, by, Y, ntiles);       // all_y
}